// Round 6
// baseline (132.704 us; speedup 1.0000x reference)
//
#include <hip/hip_runtime.h>

#define CH 30
#define CELLS 49
#define ROWF 1470          // floats per batch row
#define REGF 2940          // floats per 2-row region per tensor (11760 B = 735*16)
#define WPB 2              // waves per block (LDS-capped: 50.6 KB/block, 3 blocks/CU)
#define RPBLK 4            // rows per block
#define FULLI 11           // full 1024-B global_load_lds instrs per tensor-region
#define TAILL 31           // active lanes in the tail instr (496 B = 31*16)

__device__ __forceinline__ float waveReduce(float v) {
    #pragma unroll
    for (int o = 32; o > 0; o >>= 1) v += __shfl_xor(v, o, 64);
    return v;
}

// R6: fire-and-forget staging. R2/R4 showed the allocator serializes VGPR
// staging; R5 showed scattered gathers serialize on HBM latency (1.4 TB/s,
// VALUBusy 27%, occ 63% -- nothing saturated). The fill kernel proves 6.5
// TB/s needs only fire-and-forget issue. So: stage each wave's 2-row region
// (P+T) into LDS via 24 back-to-back global_load_lds dwordx4 (no VGPR dest,
// nothing for the allocator to serialize), one vmcnt(0), then ALL math from
// LDS (~120cy, trivially hidden). 6 waves/CU keep 141 KB/CU in flight >>
// the ~20 KB needed to cover HBM latency at the CU's BW share.
__global__ __launch_bounds__(128) void yolo_main(const float* __restrict__ pred,
                                                 const float* __restrict__ targ,
                                                 float* __restrict__ ws, int B,
                                                 int NB) {
    const int w = threadIdx.x >> 6;
    const int lane = threadIdx.x & 63;
    const int r0 = (blockIdx.x * WPB + w) * 2;   // first row of this wave's region

    __shared__ float stage[WPB][2][REGF];        // [wave][P=0/T=1][region floats]
    __shared__ float4 boxS[WPB][2 * CELLS];      // pred boxes xyxy (broadcast)
    __shared__ int clist[WPB][CELLS];
    __shared__ float sred[WPB][3];

    float cls = 0.f, objc = 0.f, coord = 0.f;

    if (r0 < B && (B - r0) >= 2) {               // wave-uniform, 2-row region
        const float* P = pred + (size_t)r0 * ROWF;
        const float* T = targ + (size_t)r0 * ROWF;
        float* lP = &stage[w][0][0];
        float* lT = &stage[w][1][0];

        // ---- issue all 24 global->LDS copies back-to-back (no VGPR dest) ----
        #pragma unroll
        for (int k = 0; k < FULLI; ++k) {
            __builtin_amdgcn_global_load_lds(
                (const __attribute__((address_space(1))) float*)(P + k * 256 + lane * 4),
                (__attribute__((address_space(3))) float*)(lP + k * 256), 16, 0, 0);
            __builtin_amdgcn_global_load_lds(
                (const __attribute__((address_space(1))) float*)(T + k * 256 + lane * 4),
                (__attribute__((address_space(3))) float*)(lT + k * 256), 16, 0, 0);
        }
        if (lane < TAILL) {                      // tail 496 B of each tensor-region
            __builtin_amdgcn_global_load_lds(
                (const __attribute__((address_space(1))) float*)(P + FULLI * 256 + lane * 4),
                (__attribute__((address_space(3))) float*)(lP + FULLI * 256), 16, 0, 0);
            __builtin_amdgcn_global_load_lds(
                (const __attribute__((address_space(1))) float*)(T + FULLI * 256 + lane * 4),
                (__attribute__((address_space(3))) float*)(lT + FULLI * 256), 16, 0, 0);
        }

        // ---- single drain; everything below reads LDS only ----
        asm volatile("s_waitcnt vmcnt(0)" ::: "memory");

        // ---- obj masks from staged t4 ----
        const int cc = lane < CELLS ? lane : CELLS - 1;
        unsigned long long m[2];
        m[0] = __ballot((lane < CELLS) && (lT[cc * CH + 4] > 0.f));
        m[1] = __ballot((lane < CELLS) && (lT[ROWF + cc * CH + 4] > 0.f));

        // ---- one-pass stream consume: cls + noobj over 1470 pairs ----
        #pragma unroll
        for (int k = 0; k < 23; ++k) {
            const int q = lane + k * 64;
            if (q < 2 * 735) {
                const int row = q >= 735;
                const int pr = q - row * 735;
                const int cell = (pr * 17477) >> 18;   // pr/15, valid to 767
                const int ch0 = 2 * (pr - cell * 15);
                const float wobj = (float)((m[row] >> cell) & 1ull);
                const float2 pq = *(const float2*)(lP + 2 * q);
                const float2 tq = *(const float2*)(lT + 2 * q);
                const float dx = pq.x - tq.x, dy = pq.y - tq.y;
                // class loss: channels 10..29, obj cells only
                cls += (ch0 >= 10) ? wobj * (dx * dx + dy * dy) : 0.f;
                // noobj conf loss (x0.5 folded): ch4 (.x) + ch9 (.y)
                const float nn = (ch0 == 4 ? dx * dx : 0.f)
                               + (ch0 == 8 ? dy * dy : 0.f);
                objc += 0.5f * (1.f - wobj) * nn;
            }
        }

        // ---- box/IoU tail per row, LDS-sourced ----
        for (int row = 0; row < 2; ++row) {
            const unsigned long long mask = m[row];
            const int nBox = 2 * __popcll(mask);
            if (!nBox) continue;                 // wave-uniform
            const float* Pr = lP + row * ROWF;
            const float* Tr = lT + row * ROWF;
            const bool isObj = (lane < CELLS) && ((mask >> lane) & 1ull);
            if (isObj) clist[w][__popcll(mask & ((1ull << lane) - 1ull))] = lane;

            for (int e = lane; e < nBox; e += 64) {
                const int c = clist[w][e >> 1];
                const float* pb = Pr + c * CH + (e & 1) * 5;
                const float cx = pb[0], cy = pb[1], bw = pb[2], bh = pb[3];
                boxS[w][e] = make_float4(cx - 0.5f * bw, cy - 0.5f * bh,
                                         cx + 0.5f * bw, cy + 0.5f * bh);
            }

            for (int e = lane; e < nBox; e += 64) {
                const int c = clist[w][e >> 1];
                const float* tb = Tr + c * CH + (e & 1) * 5;
                const float tcx = tb[0], tcy = tb[1], tw = tb[2], th = tb[3];
                const float tx1 = tcx - 0.5f * tw, ty1 = tcy - 0.5f * th;
                const float tx2 = tcx + 0.5f * tw, ty2 = tcy + 0.5f * th;
                const float ta = (tx2 - tx1) * (ty2 - ty1);
                float maxiou = 0.f;
                for (int i = 0; i < nBox; ++i) {
                    const float4 pb4 = boxS[w][i];   // uniform addr = broadcast
                    const float lx = fmaxf(pb4.x, tx1), ly = fmaxf(pb4.y, ty1);
                    const float rx = fminf(pb4.z, tx2), ry = fminf(pb4.w, ty2);
                    const float iw = fmaxf(rx - lx, 0.f), ih = fmaxf(ry - ly, 0.f);
                    const float inter = iw * ih;
                    const float pa = (pb4.z - pb4.x) * (pb4.w - pb4.y);
                    const float un = pa + ta - inter;
                    const float iou = inter / (un > 0.f ? un : 1.f);
                    maxiou = fmaxf(maxiou, iou);
                }
                if (maxiou != 0.f) {                 // cmask
                    const float* pb = Pr + c * CH + (e & 1) * 5;
                    const float dcx = pb[0] - tcx, dcy = pb[1] - tcy;
                    coord += dcx * dcx + dcy * dcy;
                    const float dw = sqrtf(pb[2]) - sqrtf(tw);
                    const float dh = sqrtf(pb[3]) - sqrtf(th);
                    coord += dw * dw + dh * dh;
                    const float dc = pb[4] - tb[4];
                    objc += dc * dc;
                }
            }
        }
    } else if (r0 < B) {
        // ---- fallback: single trailing row (B odd/B%4; never hit for B=8192).
        // R5-style direct-gather path, correct but slow.
        const float* P = pred + (size_t)r0 * ROWF;
        const float* T = targ + (size_t)r0 * ROWF;
        const int cc = lane < CELLS ? lane : CELLS - 1;
        const float t4 = T[cc * CH + 4];
        const float p4 = P[cc * CH + 4];
        const float t9 = T[cc * CH + 9];
        const float p9 = P[cc * CH + 9];
        const bool act = lane < CELLS;
        const bool isObj = act && (t4 > 0.f);
        const unsigned long long mask = __ballot(isObj);
        if (act && !isObj) {
            const float d4 = p4 - t4, d9 = p9 - t9;
            objc += 0.5f * (d4 * d4 + d9 * d9);
        }
        const int nObj = __popcll(mask);
        if (isObj) clist[w][__popcll(mask & ((1ull << lane) - 1ull))] = lane;
        if (nObj) {
            const int nCls = nObj * 20;
            for (int base = 0; base < nCls; base += 64) {
                const int idx = base + lane;
                if (idx < nCls) {
                    const int ccc = (idx * 3277) >> 16;
                    const int ch = 10 + (idx - ccc * 20);
                    const int c = clist[w][ccc];
                    const float dv = P[c * CH + ch] - T[c * CH + ch];
                    cls += dv * dv;
                }
            }
            const int nBox = 2 * nObj;
            for (int e = lane; e < nBox; e += 64) {
                const int c = clist[w][e >> 1];
                const float* pb = P + c * CH + (e & 1) * 5;
                const float cx = pb[0], cy = pb[1], bw = pb[2], bh = pb[3];
                boxS[w][e] = make_float4(cx - 0.5f * bw, cy - 0.5f * bh,
                                         cx + 0.5f * bw, cy + 0.5f * bh);
            }
            for (int e = lane; e < nBox; e += 64) {
                const int c = clist[w][e >> 1];
                const float* tb = T + c * CH + (e & 1) * 5;
                const float tcx = tb[0], tcy = tb[1], tw = tb[2], th = tb[3];
                const float tx1 = tcx - 0.5f * tw, ty1 = tcy - 0.5f * th;
                const float tx2 = tcx + 0.5f * tw, ty2 = tcy + 0.5f * th;
                const float ta = (tx2 - tx1) * (ty2 - ty1);
                float maxiou = 0.f;
                for (int i = 0; i < nBox; ++i) {
                    const float4 pb4 = boxS[w][i];
                    const float lx = fmaxf(pb4.x, tx1), ly = fmaxf(pb4.y, ty1);
                    const float rx = fminf(pb4.z, tx2), ry = fminf(pb4.w, ty2);
                    const float iw = fmaxf(rx - lx, 0.f), ih = fmaxf(ry - ly, 0.f);
                    const float inter = iw * ih;
                    const float pa = (pb4.z - pb4.x) * (pb4.w - pb4.y);
                    const float un = pa + ta - inter;
                    const float iou = inter / (un > 0.f ? un : 1.f);
                    maxiou = fmaxf(maxiou, iou);
                }
                if (maxiou != 0.f) {
                    const float* pb = P + c * CH + (e & 1) * 5;
                    const float dcx = pb[0] - tcx, dcy = pb[1] - tcy;
                    coord += dcx * dcx + dcy * dcy;
                    const float dw = sqrtf(pb[2]) - sqrtf(tw);
                    const float dh = sqrtf(pb[3]) - sqrtf(th);
                    coord += dw * dw + dh * dh;
                    const float dc = pb[4] - tb[4];
                    objc += dc * dc;
                }
            }
        }
    }

    // ---- wave reduce, then block reduce (one barrier), one triple per block ----
    cls = waveReduce(cls); objc = waveReduce(objc); coord = waveReduce(coord);
    if (lane == 0) { sred[w][0] = cls; sred[w][1] = objc; sred[w][2] = coord; }
    __syncthreads();
    if (threadIdx.x == 0) {
        float C = 0.f, O = 0.f, X = 0.f;
        #pragma unroll
        for (int k = 0; k < WPB; ++k) { C += sred[k][0]; O += sred[k][1]; X += sred[k][2]; }
        ws[blockIdx.x] = C;
        ws[NB + blockIdx.x] = O;
        ws[2 * NB + blockIdx.x] = X;
    }
}

__global__ __launch_bounds__(1024) void yolo_reduce(const float* __restrict__ ws,
                                                    float* __restrict__ out,
                                                    int NB, float invB) {
    const int tid = threadIdx.x;
    const int w = tid >> 6, lane = tid & 63;
    float c = 0.f, o = 0.f, x = 0.f;
    for (int i = tid; i < NB; i += 1024) {
        c += ws[i];
        o += ws[NB + i];
        x += ws[2 * NB + i];
    }
    c = waveReduce(c); o = waveReduce(o); x = waveReduce(x);
    __shared__ float sred[16][3];
    if (lane == 0) { sred[w][0] = c; sred[w][1] = o; sred[w][2] = x; }
    __syncthreads();
    if (tid == 0) {
        float C = 0.f, O = 0.f, X = 0.f;
        #pragma unroll
        for (int k = 0; k < 16; ++k) { C += sred[k][0]; O += sred[k][1]; X += sred[k][2]; }
        const float bcls = C * invB;
        const float bobj = O * invB;          // noobj*0.5 folded upstream
        const float bcoord = X * 5.0f * invB; // COORD_LAMBDA
        out[0] = bcls + bobj + bcoord;
        out[1] = bcls;
        out[2] = bobj;
        out[3] = bcoord;
    }
}

extern "C" void kernel_launch(void* const* d_in, const int* in_sizes, int n_in,
                              void* d_out, int out_size, void* d_ws, size_t ws_size,
                              hipStream_t stream) {
    const float* pred = (const float*)d_in[0];
    const float* targ = (const float*)d_in[1];
    float* ws = (float*)d_ws;
    float* out = (float*)d_out;
    const int B = in_sizes[0] / ROWF;
    const int NB = (B + RPBLK - 1) / RPBLK;

    yolo_main<<<NB, 128, 0, stream>>>(pred, targ, ws, B, NB);
    yolo_reduce<<<1, 1024, 0, stream>>>(ws, out, NB, 1.0f / (float)B);
}

// Round 7
// 121.987 us; speedup vs baseline: 1.0879x; 1.0879x over previous
//
#include <hip/hip_runtime.h>

#define CH 30
#define CELLS 49
#define ROWF 1470          // floats per batch row
#define WPB 4              // waves per block, one wave per row

__device__ __forceinline__ float waveReduce(float v) {
    #pragma unroll
    for (int o = 32; o > 0; o >>= 1) v += __shfl_xor(v, o, 64);
    return v;
}

// R7: minimize dependent round-trips (the cross-round diagnosis: R2/R5/R6
// were all latency-RT x occupancy bound, never VALU/BW bound).
// Per wave (one row): RT1 = 4 conf gathers -> ballot/clist/noobj.
// RT2 = ALL cls gathers (4 static rounds, nObj<=12 covers ~85% of rows;
// wave-uniform remainder loop for the rest) AND ALL box gathers (float4+conf
// for pred+targ, 2 static e-rounds = nBox<=98 always) issued back-to-back
// into named registers. RT3 = consume from registers; box/IoU phase re-reads
// nothing from global. Lean VGPR (~50), 7 KB LDS -> 6-8 waves/SIMD; 8192
// waves exactly fill 256 CUs. No mid-kernel barrier (per-wave LDS slices).
__global__ __launch_bounds__(256) void yolo_main(const float* __restrict__ pred,
                                                 const float* __restrict__ targ,
                                                 float* __restrict__ ws, int B,
                                                 int NB) {
    const int w = threadIdx.x >> 6;
    const int lane = threadIdx.x & 63;
    const int r = blockIdx.x * WPB + w;

    __shared__ float4 boxS[WPB][2 * CELLS];  // pred boxes xyxy (broadcast reads)
    __shared__ int clist[WPB][CELLS];
    __shared__ float sred[WPB][3];

    float cls = 0.f, objc = 0.f, coord = 0.f;

    if (r < B) {                             // wave-uniform
        const float* P = pred + (size_t)r * ROWF;
        const float* T = targ + (size_t)r * ROWF;

        // ---- RT1: conf gathers (4 independent loads) ----
        const int cl = lane < CELLS ? lane : CELLS - 1;
        const float t4 = T[cl * CH + 4];
        const float p4 = P[cl * CH + 4];
        const float t9 = T[cl * CH + 9];
        const float p9 = P[cl * CH + 9];

        const bool act = lane < CELLS;
        const bool isObj = act && (t4 > 0.f);
        const unsigned long long m = __ballot(isObj);

        if (act && !isObj) {                 // noobj loss (0.5 folded)
            const float d4 = p4 - t4, d9 = p9 - t9;
            objc += 0.5f * (d4 * d4 + d9 * d9);
        }

        const int nObj = __popcll(m);
        if (isObj) clist[w][__popcll(m & ((1ull << lane) - 1ull))] = lane;

        if (nObj) {                          // wave-uniform
            const int nBox = 2 * nObj;
            const int nCls = nObj * 20;

            // ---- RT2: issue ALL gathers back-to-back into named regs ----
            // cls rounds 0..3 (256 elems = nObj<=12; clamp + gate at consume)
            int cidx[4]; float cp[4], ct[4];
            #pragma unroll
            for (int j = 0; j < 4; ++j) {
                const int idx = lane + j * 64;
                const int ic = idx < nCls ? idx : nCls - 1;
                cidx[j] = idx;
                const int cc = (ic * 3277) >> 16;      // ic/20, valid <16384
                const int ch = 10 + (ic - cc * 20);
                const int c = clist[w][cc];
                cp[j] = P[c * CH + ch];
                ct[j] = T[c * CH + ch];
            }
            // box gathers: e-rounds {lane, lane+64}, clamped
            const int e0 = lane, e1 = lane + 64;
            const int c0 = clist[w][(e0 < nBox ? e0 : 0) >> 1];
            const int c1 = clist[w][(e1 < nBox ? e1 : 0) >> 1];
            const int b0 = c0 * CH + (e0 & 1) * 5;
            const int b1 = c1 * CH + (e1 & 1) * 5;
            const float4 pB0 = *(const float4*)(P + b0);
            const float4 tB0 = *(const float4*)(T + b0);
            const float pE0 = P[b0 + 4], tE0 = T[b0 + 4];
            const float4 pB1 = *(const float4*)(P + b1);
            const float4 tB1 = *(const float4*)(T + b1);
            const float pE1 = P[b1 + 4], tE1 = T[b1 + 4];

            // ---- consume: cls (static rounds + rare uniform remainder) ----
            #pragma unroll
            for (int j = 0; j < 4; ++j) {
                const float dv = cp[j] - ct[j];
                cls += (cidx[j] < nCls) ? dv * dv : 0.f;
            }
            for (int base = 256; base < nCls; base += 64) {   // nObj>12 only
                const int idx = base + lane;
                if (idx < nCls) {
                    const int cc = (idx * 3277) >> 16;
                    const int ch = 10 + (idx - cc * 20);
                    const int c = clist[w][cc];
                    const float dv = P[c * CH + ch] - T[c * CH + ch];
                    cls += dv * dv;
                }
            }

            // ---- box phase: xyxy into LDS from regs ----
            if (e0 < nBox)
                boxS[w][e0] = make_float4(pB0.x - 0.5f * pB0.z, pB0.y - 0.5f * pB0.w,
                                          pB0.x + 0.5f * pB0.z, pB0.y + 0.5f * pB0.w);
            if (e1 < nBox)
                boxS[w][e1] = make_float4(pB1.x - 0.5f * pB1.z, pB1.y - 0.5f * pB1.w,
                                          pB1.x + 0.5f * pB1.z, pB1.y + 0.5f * pB1.w);

            // ---- IoU + coord/obj losses, all operands from regs/LDS ----
            #pragma unroll
            for (int eh = 0; eh < 2; ++eh) {
                const int e = eh ? e1 : e0;
                if (e < nBox) {
                    const float4 tb = eh ? tB1 : tB0;
                    const float4 pb = eh ? pB1 : pB0;
                    const float pe = eh ? pE1 : pE0;
                    const float te = eh ? tE1 : tE0;
                    const float tx1 = tb.x - 0.5f * tb.z, ty1 = tb.y - 0.5f * tb.w;
                    const float tx2 = tb.x + 0.5f * tb.z, ty2 = tb.y + 0.5f * tb.w;
                    const float ta = (tx2 - tx1) * (ty2 - ty1);
                    float maxiou = 0.f;
                    for (int i = 0; i < nBox; ++i) {
                        const float4 pb4 = boxS[w][i];   // uniform = broadcast
                        const float lx = fmaxf(pb4.x, tx1), ly = fmaxf(pb4.y, ty1);
                        const float rx = fminf(pb4.z, tx2), ry = fminf(pb4.w, ty2);
                        const float iw = fmaxf(rx - lx, 0.f), ih = fmaxf(ry - ly, 0.f);
                        const float inter = iw * ih;
                        const float pa = (pb4.z - pb4.x) * (pb4.w - pb4.y);
                        const float un = pa + ta - inter;
                        const float iou = inter / (un > 0.f ? un : 1.f);
                        maxiou = fmaxf(maxiou, iou);
                    }
                    if (maxiou != 0.f) {                 // cmask
                        const float dcx = pb.x - tb.x, dcy = pb.y - tb.y;
                        coord += dcx * dcx + dcy * dcy;
                        const float dw = sqrtf(pb.z) - sqrtf(tb.z);
                        const float dh = sqrtf(pb.w) - sqrtf(tb.w);
                        coord += dw * dw + dh * dh;
                        const float dc = pe - te;
                        objc += dc * dc;
                    }
                }
            }
        }
    }

    // ---- wave reduce, then block reduce (one barrier), one triple per block ----
    cls = waveReduce(cls); objc = waveReduce(objc); coord = waveReduce(coord);
    if (lane == 0) { sred[w][0] = cls; sred[w][1] = objc; sred[w][2] = coord; }
    __syncthreads();
    if (threadIdx.x == 0) {
        float C = 0.f, O = 0.f, X = 0.f;
        #pragma unroll
        for (int k = 0; k < WPB; ++k) { C += sred[k][0]; O += sred[k][1]; X += sred[k][2]; }
        ws[blockIdx.x] = C;
        ws[NB + blockIdx.x] = O;
        ws[2 * NB + blockIdx.x] = X;
    }
}

__global__ __launch_bounds__(1024) void yolo_reduce(const float* __restrict__ ws,
                                                    float* __restrict__ out,
                                                    int NB, float invB) {
    const int tid = threadIdx.x;
    const int w = tid >> 6, lane = tid & 63;
    float c = 0.f, o = 0.f, x = 0.f;
    for (int i = tid; i < NB; i += 1024) {
        c += ws[i];
        o += ws[NB + i];
        x += ws[2 * NB + i];
    }
    c = waveReduce(c); o = waveReduce(o); x = waveReduce(x);
    __shared__ float sred[16][3];
    if (lane == 0) { sred[w][0] = c; sred[w][1] = o; sred[w][2] = x; }
    __syncthreads();
    if (tid == 0) {
        float C = 0.f, O = 0.f, X = 0.f;
        #pragma unroll
        for (int k = 0; k < 16; ++k) { C += sred[k][0]; O += sred[k][1]; X += sred[k][2]; }
        const float bcls = C * invB;
        const float bobj = O * invB;          // noobj*0.5 folded upstream
        const float bcoord = X * 5.0f * invB; // COORD_LAMBDA
        out[0] = bcls + bobj + bcoord;
        out[1] = bcls;
        out[2] = bobj;
        out[3] = bcoord;
    }
}

extern "C" void kernel_launch(void* const* d_in, const int* in_sizes, int n_in,
                              void* d_out, int out_size, void* d_ws, size_t ws_size,
                              hipStream_t stream) {
    const float* pred = (const float*)d_in[0];
    const float* targ = (const float*)d_in[1];
    float* ws = (float*)d_ws;
    float* out = (float*)d_out;
    const int B = in_sizes[0] / ROWF;
    const int NB = (B + WPB - 1) / WPB;

    yolo_main<<<NB, 256, 0, stream>>>(pred, targ, ws, B, NB);
    yolo_reduce<<<1, 1024, 0, stream>>>(ws, out, NB, 1.0f / (float)B);
}